// Round 3
// baseline (90.505 us; speedup 1.0000x reference)
//
#include <hip/hip_runtime.h>
#include <hip/hip_fp16.h>

#define DIN 256
#define DOUT 128
#define KNBR 32
#define MT 128        // M-tile (rows) per FC block
#define KC 64         // K-chunk (fp32 LDS = 32 KB)
#define SEG 12500     // pool segment rows (4 x 12500 = 50000; 3.2 MB fp16 each)

typedef __attribute__((ext_vector_type(4))) float f32x4;
typedef __attribute__((ext_vector_type(8))) short bf16x8;

static __device__ __forceinline__ ushort f2bf(float f) {
    uint u = __float_as_uint(f);
    return (ushort)((u + 0x7FFFu + ((u >> 16) & 1u)) >> 16);   // RNE
}

// packed f32x2 -> bf16x2 (RNE), single VALU op; no builtin on gfx950 -> asm
static __device__ __forceinline__ uint cvtpk(float lo, float hi) {
    uint r;
    asm("v_cvt_pk_bf16_f32 %0, %1, %2" : "=v"(r) : "v"(lo), "v"(hi));
    return r;
}

// async global->LDS DMA, 16 B per lane, LDS dest = wave-uniform base + lane*16
static __device__ __forceinline__ void gload_lds16(const float* g, void* l) {
    __builtin_amdgcn_global_load_lds(
        (const __attribute__((address_space(1))) void*)g,
        (__attribute__((address_space(3))) void*)l,
        16, 0, 0);
}

// One-time W fp32 -> bf16 (32768 elems)
__global__ __launch_bounds__(256) void wconv_kernel(
    const float* __restrict__ W, ushort* __restrict__ Wbf)
{
    const int idx = (blockIdx.x * 256 + threadIdx.x) * 4;
    const float4 v = *(const float4*)(W + idx);
    ushort4 o;
    o.x = f2bf(v.x); o.y = f2bf(v.y); o.z = f2bf(v.z); o.w = f2bf(v.w);
    *(ushort4*)(Wbf + idx) = o;
}

// h[n][o] = relu(feats[n][:] . W[o][:] + b[o]) via bf16 MFMA, h stored fp16.
// A staged fp32 via global_load_lds in 4 K-chunks (32 KB), source pre-swizzled;
// fragments converted with v_cvt_pk_bf16_f32 in the K loop; B streamed from L2.
__global__ __launch_bounds__(256) void fc_mfma_kernel(
    const float* __restrict__ feats, const ushort* __restrict__ Wbf,
    const float* __restrict__ bias, __half* __restrict__ h, int N)
{
    __shared__ float lds_a[MT * KC];   // 32 KB fp32 A-chunk, XOR-swizzled
    char* lds = (char*)lds_a;

    const int tid = threadIdx.x;
    const int lane = tid & 63;
    const int wv  = tid >> 6;
    const int wm  = wv >> 1, wn = wv & 1;
    const int l15 = lane & 15, lq = lane >> 4;
    const int nb  = blockIdx.x * MT;

    f32x4 acc[4][4];
    #pragma unroll
    for (int mi = 0; mi < 4; ++mi)
        #pragma unroll
        for (int ni = 0; ni < 4; ++ni) acc[mi][ni] = (f32x4){0.f, 0.f, 0.f, 0.f};

    #pragma unroll
    for (int kc = 0; kc < DIN / KC; ++kc) {
        if (kc) __syncthreads();   // prior chunk's ds_reads done before overwrite

        // ---- stage A chunk: 8 DMA issues/wave, 4 rows x 64 floats each ----
        // LDS linear: lane l -> row (l>>4), col16 (l&15). Pre-swizzle the
        // GLOBAL source so LDS ends up XOR-swizzled: col16_src = (l&15)^(row&7).
        #pragma unroll
        for (int it = 0; it < 8; ++it) {
            const int row = wv * 32 + it * 4 + (lane >> 4);
            const int c4  = (lane & 15) ^ (row & 7);       // float4 index in chunk
            int grow = nb + row; if (grow > N - 1) grow = N - 1;
            const float* src = feats + (size_t)grow * DIN + kc * KC + c4 * 4;
            gload_lds16(src, lds + (size_t)(wv * 32 + it * 4) * KC * 4);
        }

        // ---- B fragments for this chunk (ks = kc*2 + j), streamed from L2 ----
        bf16x8 breg[2][4];
        #pragma unroll
        for (int j = 0; j < 2; ++j)
            #pragma unroll
            for (int ni = 0; ni < 4; ++ni)
                breg[j][ni] = *(const bf16x8*)(
                    Wbf + (size_t)(wn * 64 + ni * 16 + l15) * DIN
                        + (kc * 2 + j) * 32 + lq * 8);

        __syncthreads();   // compiler drains vmcnt(0) -> DMA complete

        // ---- compute: 2 K-steps of 32 per chunk ----
        #pragma unroll
        for (int j = 0; j < 2; ++j) {
            bf16x8 a[4];
            #pragma unroll
            for (int mi = 0; mi < 4; ++mi) {
                const int row = wm * 64 + mi * 16 + l15;
                const int X = (row & 7) << 4;
                const int b0 = row * (KC * 4) + j * 128 + lq * 32;
                const f32x4 lo = *(const f32x4*)(lds + ((b0) ^ X));
                const f32x4 hi = *(const f32x4*)(lds + ((b0 + 16) ^ X));
                uint4 u;
                u.x = cvtpk(lo.x, lo.y); u.y = cvtpk(lo.z, lo.w);
                u.z = cvtpk(hi.x, hi.y); u.w = cvtpk(hi.z, hi.w);
                union { uint4 q; bf16x8 v; } cv; cv.q = u;
                a[mi] = cv.v;
            }
            #pragma unroll
            for (int mi = 0; mi < 4; ++mi)
                #pragma unroll
                for (int ni = 0; ni < 4; ++ni)
                    acc[mi][ni] = __builtin_amdgcn_mfma_f32_16x16x32_bf16(
                        a[mi], breg[j][ni], acc[mi][ni], 0, 0, 0);
        }
    }

    // ---- epilogue: bias + relu -> fp16 h ----
    float bcol[4];
    #pragma unroll
    for (int ni = 0; ni < 4; ++ni) bcol[ni] = bias[wn * 64 + ni * 16 + l15];

    #pragma unroll
    for (int mi = 0; mi < 4; ++mi) {
        const int rbase = nb + wm * 64 + mi * 16 + lq * 4;
        #pragma unroll
        for (int ni = 0; ni < 4; ++ni) {
            const int col = wn * 64 + ni * 16 + l15;
            #pragma unroll
            for (int r = 0; r < 4; ++r) {
                const int n = rbase + r;
                if (n < N) {
                    const float v = fmaxf(acc[mi][ni][r] + bcol[ni], 0.f);
                    h[(size_t)n * DOUT + col] = __float2half_rn(v);
                }
            }
        }
    }
}

// pooled[n][:] = mean_k h[edge[n][k]][:], gathered in 4 h-segment phases so the
// active working set (3.2 MB) fits each XCD's 4 MB L2.
struct Half4 { __half2 a, b; };

__global__ __launch_bounds__(256) void pool_kernel(
    const __half* __restrict__ h, const int* __restrict__ edge,
    float* __restrict__ out, int N)
{
    const int lane = threadIdx.x & 63;
    const int grp  = lane >> 5;                 // node sub-group within wave
    const int l31  = lane & 31;
    const int wv   = threadIdx.x >> 6;
    const int node = blockIdx.x * 8 + wv * 2 + grp;   // N % 8 == 0

    // lane-private neighbor index (coalesced), classify into 4 segments
    const int myidx = edge[(size_t)node * KNBR + l31];
    const int t = myidx >= 2 * SEG;
    const int u = myidx >= (t ? 3 * SEG : SEG);
    const unsigned long long B1 = __ballot(t);
    const unsigned long long B0 = __ballot(u);

    const Half4* h4 = (const Half4*)h;          // row stride = DOUT/4 = 32
    float4 acc = {0.f, 0.f, 0.f, 0.f};

    #pragma unroll
    for (int s = 0; s < 4; ++s) {
        const unsigned long long m64 =
            ((s & 2) ? B1 : ~B1) & ((s & 1) ? B0 : ~B0);
        uint m = grp ? (uint)(m64 >> 32) : (uint)m64;
        while (m) {
            const int k = __ffs(m) - 1; m &= m - 1;
            const int idxk = __shfl(myidx, k + (grp << 5));
            const Half4 v = h4[(size_t)idxk * (DOUT / 4) + l31];
            const float2 fa = __half22float2(v.a);
            const float2 fb = __half22float2(v.b);
            acc.x += fa.x; acc.y += fa.y; acc.z += fb.x; acc.w += fb.y;
        }
    }

    const float sc = 1.0f / (float)KNBR;
    float4 r;
    r.x = acc.x * sc; r.y = acc.y * sc; r.z = acc.z * sc; r.w = acc.w * sc;
    ((float4*)out)[(size_t)node * (DOUT / 4) + l31] = r;
}

extern "C" void kernel_launch(void* const* d_in, const int* in_sizes, int n_in,
                              void* d_out, int out_size, void* d_ws, size_t ws_size,
                              hipStream_t stream) {
    // dict order: ids, feats, W, b, edge_dict, G, ite
    const float* feats = (const float*)d_in[1];
    const float* W     = (const float*)d_in[2];
    const float* bias  = (const float*)d_in[3];
    const int*   edge  = (const int*)d_in[4];
    float* out = (float*)d_out;

    const int N = in_sizes[1] / DIN;            // 50000
    __half* h   = (__half*)d_ws;                // N*DOUT*2 = 12.8 MB
    ushort* Wbf = (ushort*)((char*)d_ws + (size_t)N * DOUT * sizeof(__half));

    wconv_kernel<<<(DOUT * DIN) / 1024, 256, 0, stream>>>(W, Wbf);
    fc_mfma_kernel<<<(N + MT - 1) / MT, 256, 0, stream>>>(feats, Wbf, bias, h, N);
    pool_kernel<<<N / 8, 256, 0, stream>>>(h, edge, out, N);
}

// Round 4
// 73.237 us; speedup vs baseline: 1.2358x; 1.2358x over previous
//
#include <hip/hip_runtime.h>
#include <hip/hip_fp16.h>

#define DIN 256
#define DOUT 128
#define KNBR 32
#define MT 128        // M-tile (rows) per FC block
#define KC 64         // K-chunk (fp32 LDS = 32 KB)
#define SEG 12500     // pool segment rows (4 x 12500 = 50000; 3.2 MB fp16 each)

typedef __attribute__((ext_vector_type(4))) float f32x4;
typedef __attribute__((ext_vector_type(8))) short bf16x8;

static __device__ __forceinline__ ushort f2bf(float f) {
    uint u = __float_as_uint(f);
    return (ushort)((u + 0x7FFFu + ((u >> 16) & 1u)) >> 16);   // RNE
}

// packed f32x2 -> bf16x2 (RNE); no builtin on gfx950 -> inline asm
static __device__ __forceinline__ uint cvtpk(float lo, float hi) {
    uint r;
    asm("v_cvt_pk_bf16_f32 %0, %1, %2" : "=v"(r) : "v"(lo), "v"(hi));
    return r;
}

// async global->LDS DMA, 16 B per lane, LDS dest = wave-uniform base + lane*16
static __device__ __forceinline__ void gload_lds16(const float* g, void* l) {
    __builtin_amdgcn_global_load_lds(
        (const __attribute__((address_space(1))) void*)g,
        (__attribute__((address_space(3))) void*)l,
        16, 0, 0);
}

// One-time W fp32 -> bf16 (32768 elems)
__global__ __launch_bounds__(256) void wconv_kernel(
    const float* __restrict__ W, ushort* __restrict__ Wbf)
{
    const int idx = (blockIdx.x * 256 + threadIdx.x) * 4;
    const float4 v = *(const float4*)(W + idx);
    ushort4 o;
    o.x = f2bf(v.x); o.y = f2bf(v.y); o.z = f2bf(v.z); o.w = f2bf(v.w);
    *(ushort4*)(Wbf + idx) = o;
}

// h[n][o] = relu(feats[n][:] . W[o][:] + b[o]) via bf16 MFMA, h stored fp16.
// A staged fp32 via global_load_lds in 4 K-chunks (32 KB), source pre-swizzled;
// fragments converted with v_cvt_pk_bf16_f32 in the K loop; B streamed from L2.
__global__ __launch_bounds__(256) void fc_mfma_kernel(
    const float* __restrict__ feats, const ushort* __restrict__ Wbf,
    const float* __restrict__ bias, __half* __restrict__ h, int N)
{
    __shared__ float lds_a[MT * KC];   // 32 KB fp32 A-chunk, XOR-swizzled
    char* lds = (char*)lds_a;

    const int tid = threadIdx.x;
    const int lane = tid & 63;
    const int wv  = tid >> 6;
    const int wm  = wv >> 1, wn = wv & 1;
    const int l15 = lane & 15, lq = lane >> 4;
    const int nb  = blockIdx.x * MT;

    f32x4 acc[4][4];
    #pragma unroll
    for (int mi = 0; mi < 4; ++mi)
        #pragma unroll
        for (int ni = 0; ni < 4; ++ni) acc[mi][ni] = (f32x4){0.f, 0.f, 0.f, 0.f};

    #pragma unroll
    for (int kc = 0; kc < DIN / KC; ++kc) {
        if (kc) __syncthreads();   // prior chunk's ds_reads done before overwrite

        // ---- stage A chunk: 8 DMA issues/wave, 4 rows x 64 floats each ----
        // LDS linear: lane l -> row (l>>4), col16 (l&15). Pre-swizzle the
        // GLOBAL source so LDS ends up XOR-swizzled: col16_src = (l&15)^(row&7).
        #pragma unroll
        for (int it = 0; it < 8; ++it) {
            const int row = wv * 32 + it * 4 + (lane >> 4);
            const int c4  = (lane & 15) ^ (row & 7);       // float4 index in chunk
            int grow = nb + row; if (grow > N - 1) grow = N - 1;
            const float* src = feats + (size_t)grow * DIN + kc * KC + c4 * 4;
            gload_lds16(src, lds + (size_t)(wv * 32 + it * 4) * KC * 4);
        }

        // ---- B fragments for this chunk (ks = kc*2 + j), streamed from L2 ----
        bf16x8 breg[2][4];
        #pragma unroll
        for (int j = 0; j < 2; ++j)
            #pragma unroll
            for (int ni = 0; ni < 4; ++ni)
                breg[j][ni] = *(const bf16x8*)(
                    Wbf + (size_t)(wn * 64 + ni * 16 + l15) * DIN
                        + (kc * 2 + j) * 32 + lq * 8);

        __syncthreads();   // compiler drains vmcnt(0) -> DMA complete

        // ---- compute: 2 K-steps of 32 per chunk ----
        #pragma unroll
        for (int j = 0; j < 2; ++j) {
            bf16x8 a[4];
            #pragma unroll
            for (int mi = 0; mi < 4; ++mi) {
                const int row = wm * 64 + mi * 16 + l15;
                const int X = (row & 7) << 4;
                const int b0 = row * (KC * 4) + j * 128 + lq * 32;
                const f32x4 lo = *(const f32x4*)(lds + ((b0) ^ X));
                const f32x4 hi = *(const f32x4*)(lds + ((b0 + 16) ^ X));
                uint4 u;
                u.x = cvtpk(lo.x, lo.y); u.y = cvtpk(lo.z, lo.w);
                u.z = cvtpk(hi.x, hi.y); u.w = cvtpk(hi.z, hi.w);
                union { uint4 q; bf16x8 v; } cv; cv.q = u;
                a[mi] = cv.v;
            }
            #pragma unroll
            for (int mi = 0; mi < 4; ++mi)
                #pragma unroll
                for (int ni = 0; ni < 4; ++ni)
                    acc[mi][ni] = __builtin_amdgcn_mfma_f32_16x16x32_bf16(
                        a[mi], breg[j][ni], acc[mi][ni], 0, 0, 0);
        }
    }

    // ---- epilogue: bias + relu -> fp16 h ----
    float bcol[4];
    #pragma unroll
    for (int ni = 0; ni < 4; ++ni) bcol[ni] = bias[wn * 64 + ni * 16 + l15];

    #pragma unroll
    for (int mi = 0; mi < 4; ++mi) {
        const int rbase = nb + wm * 64 + mi * 16 + lq * 4;
        #pragma unroll
        for (int ni = 0; ni < 4; ++ni) {
            const int col = wn * 64 + ni * 16 + l15;
            #pragma unroll
            for (int r = 0; r < 4; ++r) {
                const int n = rbase + r;
                if (n < N) {
                    const float v = fmaxf(acc[mi][ni][r] + bcol[ni], 0.f);
                    h[(size_t)n * DOUT + col] = __float2half_rn(v);
                }
            }
        }
    }
}

// pooled[n][:] = mean_k h[edge[n][k]][:]
// 8 nodes / 256-thr block, 32 lanes per node. Per node: counting-sort the 32
// neighbor indices by h-segment (4 x 12500 rows = 3.2 MB, fits per-XCD L2)
// into LDS, then a fully-unrolled independent-load gather over sorted order.
// Sorted sweep => co-resident blocks touch the same h segment together (L2
// locality) WITHOUT the round-3 ffs serialization.
struct Half4 { __half2 a, b; };

__global__ __launch_bounds__(256) void pool_kernel(
    const __half* __restrict__ h, const int* __restrict__ edge,
    float* __restrict__ out, int N)
{
    __shared__ int sorted[8 * KNBR];   // 1 KB

    const int lane = threadIdx.x & 63;
    const int grp  = lane >> 5;                 // node sub-group within wave
    const int l31  = lane & 31;
    const int wv   = threadIdx.x >> 6;
    const int nl   = wv * 2 + grp;              // node_local 0..7
    const int node = blockIdx.x * 8 + nl;       // N % 8 == 0

    // ---- load my neighbor index (coalesced) and counting-sort by segment ----
    const int myidx = edge[(size_t)node * KNBR + l31];
    const int seg = (myidx >= SEG) + (myidx >= 2 * SEG) + (myidx >= 3 * SEG);

    const unsigned long long f0 = __ballot(seg & 1);
    const unsigned long long f1 = __ballot(seg & 2);
    const uint b0 = grp ? (uint)(f0 >> 32) : (uint)f0;
    const uint b1 = grp ? (uint)(f1 >> 32) : (uint)f1;

    const uint ms = ((seg & 1) ? b0 : ~b0) & ((seg & 2) ? b1 : ~b1);
    const int rank = __popc(ms & ((1u << l31) - 1));
    const int c0 = __popc(~b0 & ~b1);
    const int c1 = __popc(b0 & ~b1);
    const int c2 = __popc(~b0 & b1);
    const int off = (seg > 0 ? c0 : 0) + (seg > 1 ? c1 : 0) + (seg > 2 ? c2 : 0);

    sorted[nl * KNBR + off + rank] = myidx;
    __syncthreads();

    // ---- gather-mean over sorted order: 32 independent loads in flight ----
    const Half4* h4 = (const Half4*)h;          // row stride = DOUT/4 = 32
    const int* sl = &sorted[nl * KNBR];

    float4 acc = {0.f, 0.f, 0.f, 0.f};
    #pragma unroll
    for (int k = 0; k < KNBR; ++k) {
        const int idxk = sl[k];                 // uniform per group -> broadcast
        const Half4 v = h4[(size_t)idxk * (DOUT / 4) + l31];
        const float2 fa = __half22float2(v.a);
        const float2 fb = __half22float2(v.b);
        acc.x += fa.x; acc.y += fa.y; acc.z += fb.x; acc.w += fb.y;
    }

    const float sc = 1.0f / (float)KNBR;
    float4 r;
    r.x = acc.x * sc; r.y = acc.y * sc; r.z = acc.z * sc; r.w = acc.w * sc;
    ((float4*)out)[(size_t)node * (DOUT / 4) + l31] = r;
}

extern "C" void kernel_launch(void* const* d_in, const int* in_sizes, int n_in,
                              void* d_out, int out_size, void* d_ws, size_t ws_size,
                              hipStream_t stream) {
    // dict order: ids, feats, W, b, edge_dict, G, ite
    const float* feats = (const float*)d_in[1];
    const float* W     = (const float*)d_in[2];
    const float* bias  = (const float*)d_in[3];
    const int*   edge  = (const int*)d_in[4];
    float* out = (float*)d_out;

    const int N = in_sizes[1] / DIN;            // 50000
    __half* h   = (__half*)d_ws;                // N*DOUT*2 = 12.8 MB
    ushort* Wbf = (ushort*)((char*)d_ws + (size_t)N * DOUT * sizeof(__half));

    wconv_kernel<<<(DOUT * DIN) / 1024, 256, 0, stream>>>(W, Wbf);
    fc_mfma_kernel<<<(N + MT - 1) / MT, 256, 0, stream>>>(feats, Wbf, bias, h, N);
    pool_kernel<<<N / 8, 256, 0, stream>>>(h, edge, out, N);
}